// Round 7
// baseline (1260.932 us; speedup 1.0000x reference)
//
#include <hip/hip_runtime.h>
#include <hip/hip_bf16.h>
#include <math.h>

#define D_ 512
#define K_ 8
#define L_ 64
#define Q_ 4096
#define C_ 4096
#define N_ (C_ * K_)   // 32768 rows of P viewed as [N][D]

typedef short short8 __attribute__((ext_vector_type(8)));
typedef float f32x4 __attribute__((ext_vector_type(4)));

static __device__ __forceinline__ void split2(float v, unsigned short& h, unsigned short& l) {
    __hip_bfloat16 hh = __float2bfloat16(v);
    float r = v - __bfloat162float(hh);
    __hip_bfloat16 ll = __float2bfloat16(r);
    h = *reinterpret_cast<unsigned short*>(&hh);
    l = *reinterpret_cast<unsigned short*>(&ll);
}

#define ASYNC_COPY16(gp, lp)                                                        \
    __builtin_amdgcn_global_load_lds((const __attribute__((address_space(1))) void*)(gp), \
                                     (__attribute__((address_space(3))) void*)(lp), \
                                     16, 0, 0)

// ---------------------------------------------------------------------------
// Prep kernels: transposes + fp32 -> bf16 hi/lo splits
// ---------------------------------------------------------------------------
__global__ void transpose_M_split(const float* __restrict__ M,
                                  unsigned short* __restrict__ Mh,
                                  unsigned short* __restrict__ Ml) {
    int idx = blockIdx.x * blockDim.x + threadIdx.x;   // over (K*D)*D, out [k*D+j][i]
    int i = idx & (D_ - 1);
    int n2 = idx >> 9;
    int j = n2 & (D_ - 1);
    int k = n2 >> 9;
    float v = M[((size_t)i * D_ + j) * K_ + k];
    split2(v, Mh[idx], Ml[idx]);
}

__global__ void split_f32(const float* __restrict__ x,
                          unsigned short* __restrict__ hi,
                          unsigned short* __restrict__ lo) {
    int i = blockIdx.x * blockDim.x + threadIdx.x;
    split2(x[i], hi[i], lo[i]);
}

__global__ void transpose_split_classT(const float* __restrict__ x,   // class [C][D]
                                       unsigned short* __restrict__ Th,
                                       unsigned short* __restrict__ Tl) {
    int idx = blockIdx.x * blockDim.x + threadIdx.x;   // out [d][c]
    int c = idx & (C_ - 1);
    int d = idx >> 12;
    float v = x[(size_t)c * D_ + d];
    split2(v, Th[idx], Tl[idx]);
}

// ---------------------------------------------------------------------------
// Pipelined MFMA NT-GEMM core, 16x16x32 bf16, bf16x3 split product.
// Block tile 128x128, BK=32; wave tile 128x32 (no cross-wave B dup).
// A: TRIPLE-buffered LDS via global_load_lds (XOR-swizzled), prefetch
//    distance 2, issued AFTER the barrier (WAR-safe: a wave issuing
//    stage(it+2) implies all waves passed the body-it barrier, so no wave
//    still reads buf (it+2)%3 == (it-1)%3).
// B: direct global->VGPR, double-buffered, distance 1.
// Sync: raw s_barrier + manual s_waitcnt vmcnt(4) -- keeps the newest
//    A-stage in flight across the barrier (the AITER pattern). stage(it) is
//    >=8 VMEM instructions old at the body-it wait, so vmcnt(4) always
//    drains it; B register deps are compiler-protected.
// ---------------------------------------------------------------------------
#define BM 128
#define BN 128
#define BNW 32
#define BKK 32

__device__ __forceinline__ void mfma_core(
    const unsigned short* __restrict__ Agh, const unsigned short* __restrict__ Agl,
    const unsigned short* __restrict__ Bgh, const unsigned short* __restrict__ Bgl,
    int lda, int ldb, int kd, int m0, int n0,
    unsigned short (*Ahb)[BM * BKK], unsigned short (*Alb)[BM * BKK],   // [3]
    f32x4 acc[8][2]) {
    const int tid = threadIdx.x;
    const int lane = tid & 63;
    const int wid = tid >> 6;
    const int fr = lane & 15;
    const int fq = lane >> 4;
    const int co = (fq ^ ((fr >> 1) & 3)) * 8;

    const unsigned short* bh0 = Bgh + (size_t)(n0 + wid * BNW + fr) * ldb + fq * 8;
    const unsigned short* bl0 = Bgl + (size_t)(n0 + wid * BNW + fr) * ldb + fq * 8;

    short8 bh[2][2], bl[2][2];

    auto stageA = [&](int buf, int j0) {
#pragma unroll
        for (int h = 0; h < 2; ++h) {
            const int i2 = h * 256 + tid;
            const int r = i2 >> 2;
            const int cg = (i2 & 3) ^ ((r >> 1) & 3);
            const int ldsoff = (h * 256 + (tid & ~63)) * 8;
            const size_t go = (size_t)(m0 + r) * lda + j0 + cg * 8;
            ASYNC_COPY16(Agh + go, &Ahb[buf][ldsoff]);
            ASYNC_COPY16(Agl + go, &Alb[buf][ldsoff]);
        }
    };
    auto loadB = [&](int buf, int j0) {
        bh[buf][0] = *(const short8*)(bh0 + j0);
        bh[buf][1] = *(const short8*)(bh0 + 16 * (size_t)ldb + j0);
        bl[buf][0] = *(const short8*)(bl0 + j0);
        bl[buf][1] = *(const short8*)(bl0 + 16 * (size_t)ldb + j0);
    };

    // Prologue order matters for the vmcnt counting: s0, B0, s1.
    stageA(0, 0);
    loadB(0, 0);
    stageA(1, BKK);

    const int niter = kd / BKK;
    int cura = 0;
    for (int it = 0; it < niter; ++it) {
        const int curb = it & 1;
        // Wait: drain everything except the newest 4 VMEM ops (the A-stage
        // issued last body). Guarantees stage(it) + B(it) complete.
        if (it + 1 < niter) {
            asm volatile("s_waitcnt vmcnt(4)" ::: "memory");
        } else {
            asm volatile("s_waitcnt vmcnt(0)" ::: "memory");
        }
        __builtin_amdgcn_s_barrier();
        asm volatile("" ::: "memory");
        // Post-barrier prefetch: B(it+1) then stage(it+2).
        if (it + 1 < niter) loadB(curb ^ 1, (it + 1) * BKK);
        if (it + 2 < niter) stageA(cura == 0 ? 2 : cura - 1, (it + 2) * BKK);
#pragma unroll
        for (int mi = 0; mi < 8; ++mi) {
            const short8 ah = *(const short8*)&Ahb[cura][(mi * 16 + fr) * BKK + co];
            const short8 al = *(const short8*)&Alb[cura][(mi * 16 + fr) * BKK + co];
#pragma unroll
            for (int ni = 0; ni < 2; ++ni) {
                acc[mi][ni] = __builtin_amdgcn_mfma_f32_16x16x32_bf16(ah, bh[curb][ni], acc[mi][ni], 0, 0, 0);
                acc[mi][ni] = __builtin_amdgcn_mfma_f32_16x16x32_bf16(ah, bl[curb][ni], acc[mi][ni], 0, 0, 0);
                acc[mi][ni] = __builtin_amdgcn_mfma_f32_16x16x32_bf16(al, bh[curb][ni], acc[mi][ni], 0, 0, 0);
            }
        }
        cura = (cura == 2) ? 0 : cura + 1;
    }
}

#define CORE_PROLOGUE                                                            \
    __shared__ __attribute__((aligned(16))) unsigned short Ahb[3][BM * BKK];     \
    __shared__ __attribute__((aligned(16))) unsigned short Alb[3][BM * BKK];     \
    const int tid = threadIdx.x;                                                 \
    const int lane = tid & 63;                                                   \
    const int wid = tid >> 6;                                                    \
    const int fr = lane & 15;                                                    \
    const int fq = lane >> 4;                                                    \
    f32x4 acc[8][2] = {};                                                        \
    (void)tid;

// ---------------------------------------------------------------------------
// gemm_P: Ph/Pl[c][k*D+j] = split( sum_i class[c,i] * M[i,j,k] )
// ---------------------------------------------------------------------------
__launch_bounds__(256, 3)
__global__ void gemm_P_mfma(const unsigned short* __restrict__ Chh,
                            const unsigned short* __restrict__ Cll,
                            const unsigned short* __restrict__ Mh,
                            const unsigned short* __restrict__ Ml,
                            unsigned short* __restrict__ Ph,
                            unsigned short* __restrict__ Pl) {
    CORE_PROLOGUE
    const int n0 = blockIdx.x * BN;   // over K*D
    const int c0 = blockIdx.y * BM;
    mfma_core(Chh, Cll, Mh, Ml, D_, D_, D_, c0, n0, Ahb, Alb, acc);
#pragma unroll
    for (int mi = 0; mi < 8; ++mi)
#pragma unroll
        for (int ni = 0; ni < 2; ++ni)
#pragma unroll
            for (int r = 0; r < 4; ++r) {
                int c = c0 + mi * 16 + fq * 4 + r;
                int n2 = n0 + wid * BNW + ni * 16 + fr;
                size_t o = (size_t)c * (K_ * D_) + n2;
                split2(acc[mi][ni][r], Ph[o], Pl[o]);
            }
}

// ---------------------------------------------------------------------------
// bilinear: other[q][c] = sb + sum_k sw[k]*relu( sum_j query[q,j]*P[c*8+k][j] )
// Grid is q-fastest: co-resident blocks share one B-panel (L2/L3 locality).
// ---------------------------------------------------------------------------
__launch_bounds__(256, 3)
__global__ void bilinear_mfma(const unsigned short* __restrict__ Qh,
                              const unsigned short* __restrict__ Ql,
                              const unsigned short* __restrict__ Ph,
                              const unsigned short* __restrict__ Pl,
                              const float* __restrict__ sw,
                              const float* __restrict__ sb,
                              float* __restrict__ other) {
    CORE_PROLOGUE
    const int q0 = blockIdx.x * BM;   // q-fastest
    const int n0 = blockIdx.y * BN;   // over N = C*K
    mfma_core(Qh, Ql, Ph, Pl, D_, D_, D_, q0, n0, Ahb, Alb, acc);
    const float wk = sw[lane & 7];
    const float bias = sb[0];
#pragma unroll
    for (int mi = 0; mi < 8; ++mi)
#pragma unroll
        for (int ni = 0; ni < 2; ++ni)
#pragma unroll
            for (int r = 0; r < 4; ++r) {
                float v = wk * fmaxf(acc[mi][ni][r], 0.f);
                v += __shfl_xor(v, 1);
                v += __shfl_xor(v, 2);
                v += __shfl_xor(v, 4);
                if ((lane & 7) == 0) {
                    int q = q0 + mi * 16 + fq * 4 + r;
                    int c = (n0 + wid * BNW + ni * 16 + fr) >> 3;
                    other[(size_t)q * C_ + c] = v + bias;
                }
            }
}

// ---------------------------------------------------------------------------
// gemm_qf (split-K=4 over grid.z): qfp[z][q][d] = sum_{c in quarter} probs*classT
// ---------------------------------------------------------------------------
__launch_bounds__(256, 3)
__global__ void gemm_qf_mfma(const unsigned short* __restrict__ Sh,
                             const unsigned short* __restrict__ Sl,
                             const unsigned short* __restrict__ Th,
                             const unsigned short* __restrict__ Tl,
                             float* __restrict__ qfp_base) {
    CORE_PROLOGUE
    const int n0 = blockIdx.x * BN;   // over D
    const int q0 = blockIdx.y * BM;
    const int zoff = blockIdx.z * (C_ / 4);
    float* qfp = qfp_base + (size_t)blockIdx.z * Q_ * D_;
    mfma_core(Sh + zoff, Sl + zoff, Th + zoff, Tl + zoff,
              C_, C_, C_ / 4, q0, n0, Ahb, Alb, acc);
#pragma unroll
    for (int mi = 0; mi < 8; ++mi)
#pragma unroll
        for (int ni = 0; ni < 2; ++ni)
#pragma unroll
            for (int r = 0; r < 4; ++r) {
                int q = q0 + mi * 16 + fq * 4 + r;
                int d = n0 + wid * BNW + ni * 16 + fr;
                qfp[(size_t)q * D_ + d] = acc[mi][ni][r];
            }
}

// ---------------------------------------------------------------------------
// Softmax over C per row; emits probs as split bf16 hi/lo. Row in registers.
// ---------------------------------------------------------------------------
__launch_bounds__(256)
__global__ void softmax_split(const float* __restrict__ other,
                              unsigned short* __restrict__ Sh,
                              unsigned short* __restrict__ Sl) {
    const int q = blockIdx.x;
    const float* row = other + (size_t)q * C_;
    const int tid = threadIdx.x;
    __shared__ float red[4];
    float v[16];
    float m = -1e30f;
#pragma unroll
    for (int it = 0; it < 16; ++it) {
        v[it] = row[tid + it * 256];
        m = fmaxf(m, v[it]);
    }
#pragma unroll
    for (int off = 32; off; off >>= 1) m = fmaxf(m, __shfl_down(m, off));
    if ((tid & 63) == 0) red[tid >> 6] = m;
    __syncthreads();
    m = fmaxf(fmaxf(red[0], red[1]), fmaxf(red[2], red[3]));
    __syncthreads();
    float s = 0.f;
#pragma unroll
    for (int it = 0; it < 16; ++it) {
        v[it] = __expf(v[it] - m);
        s += v[it];
    }
#pragma unroll
    for (int off = 32; off; off >>= 1) s += __shfl_down(s, off);
    if ((tid & 63) == 0) red[tid >> 6] = s;
    __syncthreads();
    const float inv = 1.f / (red[0] + red[1] + red[2] + red[3]);
#pragma unroll
    for (int it = 0; it < 16; ++it) {
        size_t o = (size_t)q * C_ + tid + it * 256;
        split2(v[it] * inv, Sh[o], Sl[o]);
    }
}

// ---------------------------------------------------------------------------
// hash[q][l] = tanh( sum_d (sum_z qfp[z] + query)[q][d]*hash_w[l][d] + hb[l] )
// ---------------------------------------------------------------------------
__launch_bounds__(256)
__global__ void hash_kernel(const float* __restrict__ qfp_base,
                            const float* __restrict__ Qv,
                            const float* __restrict__ hw,
                            const float* __restrict__ hb,
                            float* __restrict__ out) {
    __shared__ float sqf[4 * D_];
    const int q0 = blockIdx.x * 4;
    const int tid = threadIdx.x;
    {
        const float4* s0 = (const float4*)&qfp_base[(size_t)q0 * D_];
        const float4* s1 = (const float4*)&qfp_base[(size_t)Q_ * D_ + q0 * D_];
        const float4* s2 = (const float4*)&qfp_base[(size_t)2 * Q_ * D_ + q0 * D_];
        const float4* s3 = (const float4*)&qfp_base[(size_t)3 * Q_ * D_ + q0 * D_];
        const float4* s4 = (const float4*)&Qv[(size_t)q0 * D_];
        float4* dst = (float4*)sqf;
#pragma unroll
        for (int it = 0; it < 2; ++it) {
            int i = tid + it * 256;
            float4 a = s0[i], b = s1[i], c = s2[i], d = s3[i], e = s4[i];
            float4 o = {a.x + b.x + c.x + d.x + e.x, a.y + b.y + c.y + d.y + e.y,
                        a.z + b.z + c.z + d.z + e.z, a.w + b.w + c.w + d.w + e.w};
            dst[i] = o;
        }
    }
    __syncthreads();
    const int l = tid % L_;
    const int qi = tid / L_;
    float s = hb[l];
    const float* wrow = &hw[(size_t)l * D_];
    const float* xrow = &sqf[qi * D_];
#pragma unroll 4
    for (int d = 0; d < D_; d += 4) {
        float4 w4 = *(const float4*)&wrow[d];
        float4 x4 = *(const float4*)&xrow[d];
        s += x4.x * w4.x + x4.y * w4.y + x4.z * w4.z + x4.w * w4.w;
    }
    out[(size_t)(q0 + qi) * L_ + l] = tanhf(s);
}

// ---------------------------------------------------------------------------
extern "C" void kernel_launch(void* const* d_in, const int* in_sizes, int n_in,
                              void* d_out, int out_size, void* d_ws, size_t ws_size,
                              hipStream_t stream) {
    const float* class_v = (const float*)d_in[0];
    const float* query_v = (const float*)d_in[1];
    const float* M       = (const float*)d_in[2];
    const float* score_w = (const float*)d_in[3];
    const float* score_b = (const float*)d_in[4];
    const float* hash_w  = (const float*)d_in[5];
    const float* hash_b  = (const float*)d_in[6];
    float* out = (float*)d_out;

    // Workspace (142.6 MB, same footprint as rounds 1-6):
    //  [0,     33.5M)  Ph            -> Sh (probs hi) after softmax
    //  [33.5M, 67M)    Pl            -> Sl (probs lo)
    //  [67M,   134.2M) other (fp32 Q*C logits)
    //                  prep aliases (dead once bilinear writes other):
    //                    Mh/Ml at +0/+4.2M, Ch/Cl at +8.4M/+12.6M
    //                  post-softmax alias: qfp[4] at +0 (4 x 8.4M fp32)
    //  [134.2M,142.6M) scratch: Qh/Ql (bf16)  -> Th/Tl (classT) after bilinear
    char* base = (char*)d_ws;
    unsigned short* Ph = (unsigned short*)base;
    unsigned short* Pl = (unsigned short*)(base + (size_t)33554432);
    char* oreg          = base + (size_t)67108864;
    float* other        = (float*)oreg;
    unsigned short* Mh  = (unsigned short*)oreg;
    unsigned short* Ml  = (unsigned short*)(oreg + (size_t)4194304);
    unsigned short* Chh = (unsigned short*)(oreg + (size_t)8388608);
    unsigned short* Cll = (unsigned short*)(oreg + (size_t)12582912);
    float* qfp          = (float*)oreg;
    char* scratch = base + (size_t)134217728;
    unsigned short* Qh = (unsigned short*)scratch;
    unsigned short* Ql = (unsigned short*)(scratch + (size_t)4194304);
    unsigned short* Th = (unsigned short*)scratch;
    unsigned short* Tl = (unsigned short*)(scratch + (size_t)4194304);
    unsigned short* Sh = Ph;
    unsigned short* Sl = Pl;

    transpose_M_split<<<(K_ * D_ * D_) / 256, 256, 0, stream>>>(M, Mh, Ml);
    split_f32<<<(C_ * D_) / 256, 256, 0, stream>>>(class_v, Chh, Cll);
    split_f32<<<(Q_ * D_) / 256, 256, 0, stream>>>(query_v, Qh, Ql);
    gemm_P_mfma<<<dim3((K_ * D_) / BN, C_ / BM), 256, 0, stream>>>(Chh, Cll, Mh, Ml, Ph, Pl);
    bilinear_mfma<<<dim3(Q_ / BM, N_ / BN), 256, 0, stream>>>(Qh, Ql, Ph, Pl,
                                                              score_w, score_b, other);
    softmax_split<<<Q_, 256, 0, stream>>>(other, Sh, Sl);
    transpose_split_classT<<<(C_ * D_) / 256, 256, 0, stream>>>(class_v, Th, Tl);
    gemm_qf_mfma<<<dim3(D_ / BN, Q_ / BM, 4), 256, 0, stream>>>(Sh, Sl, Th, Tl, qfp);
    hash_kernel<<<Q_ / 4, 256, 0, stream>>>(qfp, query_v, hash_w, hash_b, out);
}

// Round 8
// 759.793 us; speedup vs baseline: 1.6596x; 1.6596x over previous
//
#include <hip/hip_runtime.h>
#include <hip/hip_bf16.h>
#include <math.h>

#define D_ 512
#define K_ 8
#define L_ 64
#define Q_ 4096
#define C_ 4096
#define N_ (C_ * K_)   // 32768 rows of P viewed as [N][D]

typedef short short8 __attribute__((ext_vector_type(8)));
typedef float f32x4 __attribute__((ext_vector_type(4)));

static __device__ __forceinline__ void split2(float v, unsigned short& h, unsigned short& l) {
    __hip_bfloat16 hh = __float2bfloat16(v);
    float r = v - __bfloat162float(hh);
    __hip_bfloat16 ll = __float2bfloat16(r);
    h = *reinterpret_cast<unsigned short*>(&hh);
    l = *reinterpret_cast<unsigned short*>(&ll);
}

#define ASYNC_COPY16(gp, lp)                                                        \
    __builtin_amdgcn_global_load_lds((const __attribute__((address_space(1))) void*)(gp), \
                                     (__attribute__((address_space(3))) void*)(lp), \
                                     16, 0, 0)

// ---------------------------------------------------------------------------
// Prep kernels: transposes + fp32 -> bf16 hi/lo splits
// ---------------------------------------------------------------------------
__global__ void transpose_M_split(const float* __restrict__ M,
                                  unsigned short* __restrict__ Mh,
                                  unsigned short* __restrict__ Ml) {
    int idx = blockIdx.x * blockDim.x + threadIdx.x;   // over (K*D)*D, out [k*D+j][i]
    int i = idx & (D_ - 1);
    int n2 = idx >> 9;
    int j = n2 & (D_ - 1);
    int k = n2 >> 9;
    float v = M[((size_t)i * D_ + j) * K_ + k];
    split2(v, Mh[idx], Ml[idx]);
}

__global__ void split_f32(const float* __restrict__ x,
                          unsigned short* __restrict__ hi,
                          unsigned short* __restrict__ lo) {
    int i = blockIdx.x * blockDim.x + threadIdx.x;
    split2(x[i], hi[i], lo[i]);
}

__global__ void transpose_split_classT(const float* __restrict__ x,   // class [C][D]
                                       unsigned short* __restrict__ Th,
                                       unsigned short* __restrict__ Tl) {
    int idx = blockIdx.x * blockDim.x + threadIdx.x;   // out [d][c]
    int c = idx & (C_ - 1);
    int d = idx >> 12;
    float v = x[(size_t)c * D_ + d];
    split2(v, Th[idx], Tl[idx]);
}

// ---------------------------------------------------------------------------
// Pipelined MFMA NT-GEMM core, 16x16x32 bf16, bf16x3 split product.
// Block tile 128x128, BK=32; wave tile 128x32 (no cross-wave B dup).
// A: triple-buffered LDS via global_load_lds (XOR-swizzled), prefetch
//    distance 2, issued AFTER the barrier (WAR-safe).
// B: direct global->VGPR, double-buffered, distance 1.
// Sync: raw s_barrier + manual s_waitcnt vmcnt(4) (AITER pattern).
// NITER is a template constant and the loop carries #pragma unroll: every
// buffer index (cura/curb) folds to a literal, so B fragments stay in VGPRs.
// (Round-7 lesson: runtime-indexed register arrays -> scratch spill, 630 MB
// of phantom traffic, MfmaUtil 3%.)
// ---------------------------------------------------------------------------
#define BM 128
#define BN 128
#define BNW 32
#define BKK 32

template <int NITER>
__device__ __forceinline__ void mfma_core(
    const unsigned short* __restrict__ Agh, const unsigned short* __restrict__ Agl,
    const unsigned short* __restrict__ Bgh, const unsigned short* __restrict__ Bgl,
    int lda, int ldb, int m0, int n0,
    unsigned short (*Ahb)[BM * BKK], unsigned short (*Alb)[BM * BKK],   // [3]
    f32x4 acc[8][2]) {
    const int tid = threadIdx.x;
    const int lane = tid & 63;
    const int wid = tid >> 6;
    const int fr = lane & 15;
    const int fq = lane >> 4;
    const int co = (fq ^ ((fr >> 1) & 3)) * 8;

    const unsigned short* bh0 = Bgh + (size_t)(n0 + wid * BNW + fr) * ldb + fq * 8;
    const unsigned short* bl0 = Bgl + (size_t)(n0 + wid * BNW + fr) * ldb + fq * 8;

    short8 bh[2][2], bl[2][2];

    auto stageA = [&](int buf, int j0) {
#pragma unroll
        for (int h = 0; h < 2; ++h) {
            const int i2 = h * 256 + tid;
            const int r = i2 >> 2;
            const int cg = (i2 & 3) ^ ((r >> 1) & 3);
            const int ldsoff = (h * 256 + (tid & ~63)) * 8;
            const size_t go = (size_t)(m0 + r) * lda + j0 + cg * 8;
            ASYNC_COPY16(Agh + go, &Ahb[buf][ldsoff]);
            ASYNC_COPY16(Agl + go, &Alb[buf][ldsoff]);
        }
    };
    auto loadB = [&](int buf, int j0) {
        bh[buf][0] = *(const short8*)(bh0 + j0);
        bh[buf][1] = *(const short8*)(bh0 + 16 * (size_t)ldb + j0);
        bl[buf][0] = *(const short8*)(bl0 + j0);
        bl[buf][1] = *(const short8*)(bl0 + 16 * (size_t)ldb + j0);
    };

    // Prologue order matters for the vmcnt counting: s0, B0, s1 (12 VMEM ops).
    stageA(0, 0);
    loadB(0, 0);
    stageA(1, BKK);

#pragma unroll
    for (int it = 0; it < NITER; ++it) {
        const int cura = it % 3;          // compile-time after unroll
        const int curb = it & 1;
        // Drain all but the newest 4 VMEM ops (= stage(it+1)); guarantees
        // stage(it) and B(it) are complete. Steady state: 12 outstanding.
        if (it + 1 < NITER) {
            asm volatile("s_waitcnt vmcnt(4)" ::: "memory");
        } else {
            asm volatile("s_waitcnt vmcnt(0)" ::: "memory");
        }
        __builtin_amdgcn_s_barrier();
        asm volatile("" ::: "memory");
        // Post-barrier prefetch: B(it+1) then stage(it+2).
        if (it + 1 < NITER) loadB(curb ^ 1, (it + 1) * BKK);
        if (it + 2 < NITER) stageA((it + 2) % 3, (it + 2) * BKK);
#pragma unroll
        for (int mi = 0; mi < 8; ++mi) {
            const short8 ah = *(const short8*)&Ahb[cura][(mi * 16 + fr) * BKK + co];
            const short8 al = *(const short8*)&Alb[cura][(mi * 16 + fr) * BKK + co];
#pragma unroll
            for (int ni = 0; ni < 2; ++ni) {
                acc[mi][ni] = __builtin_amdgcn_mfma_f32_16x16x32_bf16(ah, bh[curb][ni], acc[mi][ni], 0, 0, 0);
                acc[mi][ni] = __builtin_amdgcn_mfma_f32_16x16x32_bf16(ah, bl[curb][ni], acc[mi][ni], 0, 0, 0);
                acc[mi][ni] = __builtin_amdgcn_mfma_f32_16x16x32_bf16(al, bh[curb][ni], acc[mi][ni], 0, 0, 0);
            }
        }
    }
}

#define CORE_PROLOGUE                                                            \
    __shared__ __attribute__((aligned(16))) unsigned short Ahb[3][BM * BKK];     \
    __shared__ __attribute__((aligned(16))) unsigned short Alb[3][BM * BKK];     \
    const int tid = threadIdx.x;                                                 \
    const int lane = tid & 63;                                                   \
    const int wid = tid >> 6;                                                    \
    const int fr = lane & 15;                                                    \
    const int fq = lane >> 4;                                                    \
    f32x4 acc[8][2] = {};                                                        \
    (void)tid;

// ---------------------------------------------------------------------------
// gemm_P: Ph/Pl[c][k*D+j] = split( sum_i class[c,i] * M[i,j,k] )
// ---------------------------------------------------------------------------
__launch_bounds__(256, 3)
__global__ void gemm_P_mfma(const unsigned short* __restrict__ Chh,
                            const unsigned short* __restrict__ Cll,
                            const unsigned short* __restrict__ Mh,
                            const unsigned short* __restrict__ Ml,
                            unsigned short* __restrict__ Ph,
                            unsigned short* __restrict__ Pl) {
    CORE_PROLOGUE
    const int n0 = blockIdx.x * BN;   // over K*D
    const int c0 = blockIdx.y * BM;
    mfma_core<D_ / BKK>(Chh, Cll, Mh, Ml, D_, D_, c0, n0, Ahb, Alb, acc);
#pragma unroll
    for (int mi = 0; mi < 8; ++mi)
#pragma unroll
        for (int ni = 0; ni < 2; ++ni)
#pragma unroll
            for (int r = 0; r < 4; ++r) {
                int c = c0 + mi * 16 + fq * 4 + r;
                int n2 = n0 + wid * BNW + ni * 16 + fr;
                size_t o = (size_t)c * (K_ * D_) + n2;
                split2(acc[mi][ni][r], Ph[o], Pl[o]);
            }
}

// ---------------------------------------------------------------------------
// bilinear: other[q][c] = sb + sum_k sw[k]*relu( sum_j query[q,j]*P[c*8+k][j] )
// Grid is q-fastest: co-resident blocks share one B-panel (L2/L3 locality).
// ---------------------------------------------------------------------------
__launch_bounds__(256, 3)
__global__ void bilinear_mfma(const unsigned short* __restrict__ Qh,
                              const unsigned short* __restrict__ Ql,
                              const unsigned short* __restrict__ Ph,
                              const unsigned short* __restrict__ Pl,
                              const float* __restrict__ sw,
                              const float* __restrict__ sb,
                              float* __restrict__ other) {
    CORE_PROLOGUE
    const int q0 = blockIdx.x * BM;   // q-fastest
    const int n0 = blockIdx.y * BN;   // over N = C*K
    mfma_core<D_ / BKK>(Qh, Ql, Ph, Pl, D_, D_, q0, n0, Ahb, Alb, acc);
    const float wk = sw[lane & 7];
    const float bias = sb[0];
#pragma unroll
    for (int mi = 0; mi < 8; ++mi)
#pragma unroll
        for (int ni = 0; ni < 2; ++ni)
#pragma unroll
            for (int r = 0; r < 4; ++r) {
                float v = wk * fmaxf(acc[mi][ni][r], 0.f);
                v += __shfl_xor(v, 1);
                v += __shfl_xor(v, 2);
                v += __shfl_xor(v, 4);
                if ((lane & 7) == 0) {
                    int q = q0 + mi * 16 + fq * 4 + r;
                    int c = (n0 + wid * BNW + ni * 16 + fr) >> 3;
                    other[(size_t)q * C_ + c] = v + bias;
                }
            }
}

// ---------------------------------------------------------------------------
// gemm_qf (split-K=8 over grid.z, kd=512 -> same NITER=16 instantiation as
// bilinear): qfp[z][q][d] = sum_{c in eighth} probs[q][c]*classT[d][c]
// ---------------------------------------------------------------------------
__launch_bounds__(256, 3)
__global__ void gemm_qf_mfma(const unsigned short* __restrict__ Sh,
                             const unsigned short* __restrict__ Sl,
                             const unsigned short* __restrict__ Th,
                             const unsigned short* __restrict__ Tl,
                             float* __restrict__ qfp_base) {
    CORE_PROLOGUE
    const int n0 = blockIdx.x * BN;   // over D
    const int q0 = blockIdx.y * BM;
    const int zoff = blockIdx.z * (C_ / 8);
    float* qfp = qfp_base + (size_t)blockIdx.z * Q_ * D_;
    mfma_core<(C_ / 8) / BKK>(Sh + zoff, Sl + zoff, Th + zoff, Tl + zoff,
                              C_, C_, q0, n0, Ahb, Alb, acc);
#pragma unroll
    for (int mi = 0; mi < 8; ++mi)
#pragma unroll
        for (int ni = 0; ni < 2; ++ni)
#pragma unroll
            for (int r = 0; r < 4; ++r) {
                int q = q0 + mi * 16 + fq * 4 + r;
                int d = n0 + wid * BNW + ni * 16 + fr;
                qfp[(size_t)q * D_ + d] = acc[mi][ni][r];
            }
}

// ---------------------------------------------------------------------------
// Softmax over C per row; emits probs as split bf16 hi/lo. Row in registers.
// ---------------------------------------------------------------------------
__launch_bounds__(256)
__global__ void softmax_split(const float* __restrict__ other,
                              unsigned short* __restrict__ Sh,
                              unsigned short* __restrict__ Sl) {
    const int q = blockIdx.x;
    const float* row = other + (size_t)q * C_;
    const int tid = threadIdx.x;
    __shared__ float red[4];
    float v[16];
    float m = -1e30f;
#pragma unroll
    for (int it = 0; it < 16; ++it) {
        v[it] = row[tid + it * 256];
        m = fmaxf(m, v[it]);
    }
#pragma unroll
    for (int off = 32; off; off >>= 1) m = fmaxf(m, __shfl_down(m, off));
    if ((tid & 63) == 0) red[tid >> 6] = m;
    __syncthreads();
    m = fmaxf(fmaxf(red[0], red[1]), fmaxf(red[2], red[3]));
    __syncthreads();
    float s = 0.f;
#pragma unroll
    for (int it = 0; it < 16; ++it) {
        v[it] = __expf(v[it] - m);
        s += v[it];
    }
#pragma unroll
    for (int off = 32; off; off >>= 1) s += __shfl_down(s, off);
    if ((tid & 63) == 0) red[tid >> 6] = s;
    __syncthreads();
    const float inv = 1.f / (red[0] + red[1] + red[2] + red[3]);
#pragma unroll
    for (int it = 0; it < 16; ++it) {
        size_t o = (size_t)q * C_ + tid + it * 256;
        split2(v[it] * inv, Sh[o], Sl[o]);
    }
}

// ---------------------------------------------------------------------------
// hash[q][l] = tanh( sum_d (sum_z qfp[z] + query)[q][d]*hash_w[l][d] + hb[l] )
// ---------------------------------------------------------------------------
__launch_bounds__(256)
__global__ void hash_kernel(const float* __restrict__ qfp_base,
                            const float* __restrict__ Qv,
                            const float* __restrict__ hw,
                            const float* __restrict__ hb,
                            float* __restrict__ out) {
    __shared__ float sqf[4 * D_];
    const int q0 = blockIdx.x * 4;
    const int tid = threadIdx.x;
    {
        float4* dst = (float4*)sqf;
#pragma unroll
        for (int it = 0; it < 2; ++it) {
            int i = tid + it * 256;
            const float4* sq = (const float4*)&Qv[(size_t)q0 * D_];
            float4 o = sq[i];
#pragma unroll
            for (int z = 0; z < 8; ++z) {
                const float4* sz = (const float4*)&qfp_base[(size_t)z * Q_ * D_ + q0 * D_];
                float4 a = sz[i];
                o.x += a.x; o.y += a.y; o.z += a.z; o.w += a.w;
            }
            dst[i] = o;
        }
    }
    __syncthreads();
    const int l = tid % L_;
    const int qi = tid / L_;
    float s = hb[l];
    const float* wrow = &hw[(size_t)l * D_];
    const float* xrow = &sqf[qi * D_];
#pragma unroll 4
    for (int d = 0; d < D_; d += 4) {
        float4 w4 = *(const float4*)&wrow[d];
        float4 x4 = *(const float4*)&xrow[d];
        s += x4.x * w4.x + x4.y * w4.y + x4.z * w4.z + x4.w * w4.w;
    }
    out[(size_t)(q0 + qi) * L_ + l] = tanhf(s);
}

// ---------------------------------------------------------------------------
extern "C" void kernel_launch(void* const* d_in, const int* in_sizes, int n_in,
                              void* d_out, int out_size, void* d_ws, size_t ws_size,
                              hipStream_t stream) {
    const float* class_v = (const float*)d_in[0];
    const float* query_v = (const float*)d_in[1];
    const float* M       = (const float*)d_in[2];
    const float* score_w = (const float*)d_in[3];
    const float* score_b = (const float*)d_in[4];
    const float* hash_w  = (const float*)d_in[5];
    const float* hash_b  = (const float*)d_in[6];
    float* out = (float*)d_out;

    // Workspace (142.6 MB, same footprint as rounds 1-7):
    //  [0,     33.5M)  Ph            -> Sh (probs hi) after softmax
    //  [33.5M, 67M)    Pl            -> Sl (probs lo)
    //  [67M,   134.2M) other (fp32 Q*C logits)
    //                  prep aliases (dead once bilinear writes other):
    //                    Mh/Ml at +0/+4.2M, Ch/Cl at +8.4M/+12.6M
    //                  post-softmax alias: qfp[8] at +0 (8 x 8.4M fp32 = 64M)
    //  [134.2M,142.6M) scratch: Qh/Ql (bf16)  -> Th/Tl (classT) after bilinear
    char* base = (char*)d_ws;
    unsigned short* Ph = (unsigned short*)base;
    unsigned short* Pl = (unsigned short*)(base + (size_t)33554432);
    char* oreg          = base + (size_t)67108864;
    float* other        = (float*)oreg;
    unsigned short* Mh  = (unsigned short*)oreg;
    unsigned short* Ml  = (unsigned short*)(oreg + (size_t)4194304);
    unsigned short* Chh = (unsigned short*)(oreg + (size_t)8388608);
    unsigned short* Cll = (unsigned short*)(oreg + (size_t)12582912);
    float* qfp          = (float*)oreg;
    char* scratch = base + (size_t)134217728;
    unsigned short* Qh = (unsigned short*)scratch;
    unsigned short* Ql = (unsigned short*)(scratch + (size_t)4194304);
    unsigned short* Th = (unsigned short*)scratch;
    unsigned short* Tl = (unsigned short*)(scratch + (size_t)4194304);
    unsigned short* Sh = Ph;
    unsigned short* Sl = Pl;

    transpose_M_split<<<(K_ * D_ * D_) / 256, 256, 0, stream>>>(M, Mh, Ml);
    split_f32<<<(C_ * D_) / 256, 256, 0, stream>>>(class_v, Chh, Cll);
    split_f32<<<(Q_ * D_) / 256, 256, 0, stream>>>(query_v, Qh, Ql);
    gemm_P_mfma<<<dim3((K_ * D_) / BN, C_ / BM), 256, 0, stream>>>(Chh, Cll, Mh, Ml, Ph, Pl);
    bilinear_mfma<<<dim3(Q_ / BM, N_ / BN), 256, 0, stream>>>(Qh, Ql, Ph, Pl,
                                                              score_w, score_b, other);
    softmax_split<<<Q_, 256, 0, stream>>>(other, Sh, Sl);
    transpose_split_classT<<<(C_ * D_) / 256, 256, 0, stream>>>(class_v, Th, Tl);
    gemm_qf_mfma<<<dim3(D_ / BN, Q_ / BM, 8), 256, 0, stream>>>(Sh, Sl, Th, Tl, qfp);
    hash_kernel<<<Q_ / 4, 256, 0, stream>>>(qfp, query_v, hash_w, hash_b, out);
}